// Round 6
// baseline (2982.333 us; speedup 1.0000x reference)
//
#include <hip/hip_runtime.h>

#define Bn 32
#define Tn 512
#define Dn 512
#define Vn 512

typedef _Float16 h1;
typedef _Float16 h8 __attribute__((ext_vector_type(8)));
typedef float f4 __attribute__((ext_vector_type(4)));

__device__ __forceinline__ float max8lds(const float* p) {
  float4 a = *(const float4*)p;
  float4 b = *(const float4*)(p + 4);
  return fmaxf(fmaxf(fmaxf(a.x, a.y), fmaxf(a.z, a.w)),
               fmaxf(fmaxf(b.x, b.y), fmaxf(b.z, b.w)));
}

// 64-lane max via DPP (row_shr 1/2/4/8 + bcast15/31), result broadcast via readlane
__device__ __forceinline__ float dpp64max(float x) {
  int t;
  t = __builtin_amdgcn_update_dpp(__float_as_int(x), __float_as_int(x), 0x111, 0xF, 0xF, false);
  x = fmaxf(x, __int_as_float(t));
  t = __builtin_amdgcn_update_dpp(__float_as_int(x), __float_as_int(x), 0x112, 0xF, 0xF, false);
  x = fmaxf(x, __int_as_float(t));
  t = __builtin_amdgcn_update_dpp(__float_as_int(x), __float_as_int(x), 0x114, 0xF, 0xF, false);
  x = fmaxf(x, __int_as_float(t));
  t = __builtin_amdgcn_update_dpp(__float_as_int(x), __float_as_int(x), 0x118, 0xF, 0xF, false);
  x = fmaxf(x, __int_as_float(t));
  t = __builtin_amdgcn_update_dpp(__float_as_int(x), __float_as_int(x), 0x142, 0xF, 0xF, false);
  x = fmaxf(x, __int_as_float(t));
  t = __builtin_amdgcn_update_dpp(__float_as_int(x), __float_as_int(x), 0x143, 0xF, 0xF, false);
  x = fmaxf(x, __int_as_float(t));
  return __int_as_float(__builtin_amdgcn_readlane(__float_as_int(x), 63));
}

// raw barrier: LDS-visibility only (no vmcnt drain -> global ops float across steps)
__device__ __forceinline__ void bar_lgkm() {
  asm volatile("s_waitcnt lgkmcnt(0)" ::: "memory");
  __builtin_amdgcn_s_barrier();
}

// ---- pruning radius: max over columns v of (max_u T[u][v] - min_u T[u][v]) ----
// grid 8, block 512; block handles 64 cols; atomicMax(float-bits) into Rout (pre-zeroed)
__global__ __launch_bounds__(512) void crf_minmax(const float* __restrict__ trans,
                                                  unsigned int* __restrict__ Rout) {
  __shared__ float smn[8][64], smx[8][64];
  const int c = threadIdx.x & 63;
  const int seg = threadIdx.x >> 6;
  const int col = (int)blockIdx.x * 64 + c;
  float mn = 3e38f, mx = -3e38f;
#pragma unroll 4
  for (int u = seg * 64; u < seg * 64 + 64; ++u) {
    float t = trans[(size_t)u * Vn + col];
    mn = fminf(mn, t); mx = fmaxf(mx, t);
  }
  smn[seg][c] = mn; smx[seg][c] = mx;
  __syncthreads();
  if (seg == 0) {
#pragma unroll
    for (int i = 1; i < 8; ++i) { mn = fminf(mn, smn[i][c]); mx = fmaxf(mx, smx[i][c]); }
    float r = dpp64max(mx - mn);  // r >= 0
    if (c == 0) atomicMax((int*)Rout, __float_as_int(r));
  }
}

// ---- E4: exp(trans) arranged as MFMA A-fragments ----
// frag element (vt, kc, lane, j) = exp(trans[u][v]),
//   u = kc*32 + 8*(lane>>4) + j,  v = vt*16 + (lane&15)
__global__ __launch_bounds__(256) void crf_build_E4(const float* __restrict__ trans,
                                                    h1* __restrict__ E4) {
  __shared__ float tl[32][17];
  const int vt = (int)blockIdx.x >> 4, kc = (int)blockIdx.x & 15;
  const int tid = threadIdx.x;
#pragma unroll
  for (int rep = 0; rep < 2; ++rep) {
    int l = tid + rep * 256;
    int ul = l >> 4, vl = l & 15;
    tl[ul][vl] = trans[(size_t)(kc * 32 + ul) * Vn + (vt * 16 + vl)];
  }
  __syncthreads();
  const int lane = tid & 63, jp = tid >> 6;
  const int g = lane >> 4, c = lane & 15;
#pragma unroll
  for (int j2 = 0; j2 < 2; ++j2) {
    int j = jp * 2 + j2;
    float e = __expf(tl[8 * g + j][c]);
    E4[((size_t)(vt * 16 + kc) * 64 + lane) * 8 + j] = (h1)e;
  }
}

// ---- emissions = X(16384x512) * W^T(512x512), f32, 64x64 tile BK=16 ----
__global__ __launch_bounds__(256) void crf_gemm(const float* __restrict__ X,
                                                const float* __restrict__ Wt,
                                                float* __restrict__ C) {
  __shared__ float As[16][68];
  __shared__ float Bs[16][68];
  const int tid = threadIdx.x;
  const int m0 = (int)(blockIdx.x >> 3) * 64;
  const int v0 = (int)(blockIdx.x & 7) * 64;
  const int lr = tid >> 2;
  const int lk = (tid & 3) * 4;
  const int ty = tid >> 4, tx = tid & 15;
  float acc[4][4] = {};
  const float* xrow = X + (size_t)(m0 + lr) * Dn + lk;
  const float* wrow = Wt + (size_t)(v0 + lr) * Dn + lk;
  for (int k0 = 0; k0 < Dn; k0 += 16) {
    float4 av = *(const float4*)(xrow + k0);
    float4 bv = *(const float4*)(wrow + k0);
    __syncthreads();
    As[lk + 0][lr] = av.x; As[lk + 1][lr] = av.y; As[lk + 2][lr] = av.z; As[lk + 3][lr] = av.w;
    Bs[lk + 0][lr] = bv.x; Bs[lk + 1][lr] = bv.y; Bs[lk + 2][lr] = bv.z; Bs[lk + 3][lr] = bv.w;
    __syncthreads();
#pragma unroll
    for (int kk = 0; kk < 16; ++kk) {
      float4 a = *(const float4*)&As[kk][ty * 4];
      float4 b4 = *(const float4*)&Bs[kk][tx * 4];
      float a_[4] = {a.x, a.y, a.z, a.w};
      float b_[4] = {b4.x, b4.y, b4.z, b4.w};
#pragma unroll
      for (int j = 0; j < 4; ++j)
#pragma unroll
        for (int i = 0; i < 4; ++i)
          acc[j][i] = fmaf(a_[j], b_[i], acc[j][i]);
    }
  }
#pragma unroll
  for (int j = 0; j < 4; ++j) {
    float4 o; o.x = acc[j][0]; o.y = acc[j][1]; o.z = acc[j][2]; o.w = acc[j][3];
    *(float4*)(C + (size_t)(m0 + ty * 4 + j) * Vn + v0 + tx * 4) = o;
  }
}

// ---- shared-memory union: forward vs viterbi roles ----
union SM {
  struct {
    __align__(16) uint4 ldsA[8 * 4 * 4 * 64];  // 128 KB: kc 12..15 A-frags
    __align__(16) h1 ph[2][Vn];                // parity-double-buffered p
    __align__(16) float wred[2][8];            // parity-double-buffered wave maxes
    __align__(16) float wred2[8];
    unsigned char padsh[Tn];
  } f;
  struct {
    __align__(16) float va2[2][Vn];
    __align__(16) unsigned short bpbuf[32][Vn];
    unsigned short tokens[Tn];
    __align__(16) unsigned long long m8[2][8];  // parity-double-buffered masks
    __align__(16) float wvals[8];
    int widxs[8];
    unsigned char padsh[Tn];
    int lastS;
  } v;
};

// ---- fused scan: blocks 0..31 forward(logZ,loglik); 32..63 viterbi+backtrace ----
__global__ __launch_bounds__(512, 2) void crf_scan(
    const float* __restrict__ emis, const float* __restrict__ trans,
    const h1* __restrict__ E4, const float* __restrict__ Rp,
    const int* __restrict__ tgt, const unsigned char* __restrict__ pad,
    unsigned short* __restrict__ bps, float* __restrict__ out_ll,
    float* __restrict__ out_tok) {
  __shared__ SM sm;

  const int tid = threadIdx.x;
  const int b = blockIdx.x & 31;
  const int role = blockIdx.x >> 5;
  const float* eb = emis + (size_t)b * Tn * Vn;
  const int w = tid >> 6;
  const int lane = tid & 63;

  if (role == 0) {
    // ========== FORWARD (logsumexp via MFMA, 1 barrier/step, DPP max) ==========
    const int g = lane >> 4, c = lane & 15;
    const int t2sel = c >> 2, r2sel = c & 3;
    const int sidx = ((16 * ((lane >> 2) & 3)) + 4 * (lane >> 4) + (lane & 3)) << 2;
    const h8* E4v = (const h8*)E4;
    h8 EA[4][12];
#pragma unroll
    for (int vt2 = 0; vt2 < 4; ++vt2)
#pragma unroll
      for (int kc = 0; kc < 12; ++kc)
        EA[vt2][kc] = E4v[(size_t)((4 * w + vt2) * 16 + kc) * 64 + lane];
    {
      const uint4* E4u = (const uint4*)E4;
#pragma unroll
      for (int vt2 = 0; vt2 < 4; ++vt2)
#pragma unroll
        for (int k2 = 0; k2 < 4; ++k2)
          sm.f.ldsA[(((w * 4 + vt2) * 4) + k2) * 64 + lane] =
              E4u[(size_t)((4 * w + vt2) * 16 + (12 + k2)) * 64 + lane];
    }
    sm.f.padsh[tid] = pad[b * Tn + tid];
    float alphaR = eb[tid];
    float ecur = eb[Vn + tid];
    {
      float r = dpp64max(alphaR);
      if (lane == 0) sm.f.wred[0][w] = r;
    }
    bar_lgkm();
    float m_used = max8lds(sm.f.wred[0]);  // exact max(alpha_0)

    for (int t = 1; t < Tn; ++t) {
      const int q = t & 1;
      float p = __expf(fminf(alphaR - m_used, 11.0f));
      sm.f.ph[q][tid] = (h1)p;
      bar_lgkm();  // ph[q] + wred[q^1] (written end of t-1) visible
      float m_next = max8lds(sm.f.wred[q ^ 1]);  // exact max(alpha_{t-1})
      float enext = (t + 1 < Tn) ? eb[(size_t)(t + 1) * Vn + tid] : 0.f;
      f4 acc0 = (f4)(0.f), acc1 = (f4)(0.f), acc2 = (f4)(0.f), acc3 = (f4)(0.f);
      const h8* phf = (const h8*)sm.f.ph[q];
#pragma unroll
      for (int kc = 0; kc < 12; ++kc) {
        h8 pb = phf[kc * 4 + g];
        acc0 = __builtin_amdgcn_mfma_f32_16x16x32_f16(EA[0][kc], pb, acc0, 0, 0, 0);
        acc1 = __builtin_amdgcn_mfma_f32_16x16x32_f16(EA[1][kc], pb, acc1, 0, 0, 0);
        acc2 = __builtin_amdgcn_mfma_f32_16x16x32_f16(EA[2][kc], pb, acc2, 0, 0, 0);
        acc3 = __builtin_amdgcn_mfma_f32_16x16x32_f16(EA[3][kc], pb, acc3, 0, 0, 0);
      }
#pragma unroll
      for (int k2 = 0; k2 < 4; ++k2) {
        h8 pb = phf[(12 + k2) * 4 + g];
        h8 a0 = *(const h8*)&sm.f.ldsA[(((w * 4 + 0) * 4) + k2) * 64 + lane];
        h8 a1 = *(const h8*)&sm.f.ldsA[(((w * 4 + 1) * 4) + k2) * 64 + lane];
        h8 a2 = *(const h8*)&sm.f.ldsA[(((w * 4 + 2) * 4) + k2) * 64 + lane];
        h8 a3 = *(const h8*)&sm.f.ldsA[(((w * 4 + 3) * 4) + k2) * 64 + lane];
        acc0 = __builtin_amdgcn_mfma_f32_16x16x32_f16(a0, pb, acc0, 0, 0, 0);
        acc1 = __builtin_amdgcn_mfma_f32_16x16x32_f16(a1, pb, acc1, 0, 0, 0);
        acc2 = __builtin_amdgcn_mfma_f32_16x16x32_f16(a2, pb, acc2, 0, 0, 0);
        acc3 = __builtin_amdgcn_mfma_f32_16x16x32_f16(a3, pb, acc3, 0, 0, 0);
      }
      // present value for v-slot 16*(c>>2)+4g+(c&3); pull via one intra-wave bpermute
      f4 at = (t2sel == 0) ? acc0 : (t2sel == 1) ? acc1 : (t2sel == 2) ? acc2 : acc3;
      float lo = (r2sel & 1) ? at[1] : at[0];
      float hi = (r2sel & 1) ? at[3] : at[2];
      float tot = (r2sel & 2) ? hi : lo;
      float tv = __int_as_float(__builtin_amdgcn_ds_bpermute(sidx, __float_as_int(tot)));
      float nv = m_used + __logf(tv) + ecur;
      if (sm.f.padsh[t]) nv = alphaR;
      alphaR = nv; ecur = enext;
      float rmx = dpp64max(nv);
      if (lane == 0) sm.f.wred[q][w] = rmx;  // visible after next iter's barrier
      m_used = m_next;
    }

    // epilogue: logZ + gold score
    __syncthreads();
    float m = max8lds(sm.f.wred[1]);  // max(alpha_511)
    float ex = __expf(alphaR - m);
#pragma unroll
    for (int off = 1; off < 64; off <<= 1) ex += __shfl_xor(ex, off);
    if (lane == 0) sm.f.wred[0][w] = ex;
    float sc;
    {
      int t = tid;
      int tg = tgt[b * Tn + t];
      float mt = sm.f.padsh[t] ? 0.f : 1.f;
      sc = eb[(size_t)t * Vn + tg] * mt;
      if (t < Tn - 1) {
        int tg1 = tgt[b * Tn + t + 1];
        float mt1 = sm.f.padsh[t + 1] ? 0.f : 1.f;
        sc += trans[(size_t)tg * Vn + tg1] * mt * mt1;
      }
    }
#pragma unroll
    for (int off = 1; off < 64; off <<= 1) sc += __shfl_xor(sc, off);
    if (lane == 0) sm.f.wred2[w] = sc;
    __syncthreads();
    if (tid == 0) {
      float s = 0.f, gg = 0.f;
      for (int i = 0; i < 8; ++i) { s += sm.f.wred[0][i]; gg += sm.f.wred2[i]; }
      out_ll[b] = gg - (m + __logf(s));
    }
  } else {
    // ========== VITERBI (1 barrier/step, wave-local threshold, batched loads) ==========
    float R = __int_as_float(((const int*)Rp)[0]) * 1.000001f + 1e-4f;
    sm.v.padsh[tid] = pad[b * Tn + tid];
    float vaR = eb[tid];
    sm.v.va2[0][tid] = vaR;
    float ecur = eb[Vn + tid];
    {
      float rmx = dpp64max(vaR);
      unsigned long long mk = __ballot(vaR >= rmx - R);
      if (lane == 0) sm.v.m8[0][w] = mk;
    }
    bar_lgkm();

    for (int t = 1; t < Tn; ++t) {
      const int cur = t & 1, prev = cur ^ 1;
      const float* va2p = sm.v.va2[prev];
      unsigned long long M[8];
#pragma unroll
      for (int i = 0; i < 4; ++i)
        ((ulonglong2*)M)[i] = ((const ulonglong2*)sm.v.m8[prev])[i];
      float enext = (t + 1 < Tn) ? eb[(size_t)(t + 1) * Vn + tid] : 0.f;
      float best = -3e38f; int arg = 0;
#pragma unroll 1
      for (int w2 = 0; w2 < 8; ++w2) {
        unsigned long long mask = M[w2];
        while (mask) {
          int u0, u1 = -1, u2 = -1, u3 = -1;
          u0 = (w2 << 6) + __ffsll(mask) - 1; mask &= mask - 1;
          if (mask) { u1 = (w2 << 6) + __ffsll(mask) - 1; mask &= mask - 1; }
          if (u1 >= 0 && mask) { u2 = (w2 << 6) + __ffsll(mask) - 1; mask &= mask - 1; }
          if (u2 >= 0 && mask) { u3 = (w2 << 6) + __ffsll(mask) - 1; mask &= mask - 1; }
          float t0 = trans[(size_t)u0 * Vn + tid], v0 = va2p[u0];
          float t1 = 0.f, v1 = 0.f, t2 = 0.f, v2 = 0.f, t3 = 0.f, v3 = 0.f;
          if (u1 >= 0) { t1 = trans[(size_t)u1 * Vn + tid]; v1 = va2p[u1]; }
          if (u2 >= 0) { t2 = trans[(size_t)u2 * Vn + tid]; v2 = va2p[u2]; }
          if (u3 >= 0) { t3 = trans[(size_t)u3 * Vn + tid]; v3 = va2p[u3]; }
          float c0 = v0 + t0;
          if (c0 > best) { best = c0; arg = u0; }
          if (u1 >= 0) { float c1 = v1 + t1; if (c1 > best) { best = c1; arg = u1; } }
          if (u2 >= 0) { float c2 = v2 + t2; if (c2 > best) { best = c2; arg = u2; } }
          if (u3 >= 0) { float c3 = v3 + t3; if (c3 > best) { best = c3; arg = u3; } }
        }
      }
      float nv = best + ecur; int bp = arg;
      if (sm.v.padsh[t]) { nv = vaR; bp = tid; }
      bps[((size_t)(t - 1) * Bn + b) * Vn + tid] = (unsigned short)bp;  // floats free
      sm.v.va2[cur][tid] = nv;
      {
        float rmx = dpp64max(nv);
        unsigned long long mk = __ballot(nv >= rmx - R);
        if (lane == 0) sm.v.m8[cur][w] = mk;
      }
      vaR = nv; ecur = enext;
      bar_lgkm();  // single barrier: va2[cur] + m8[cur] visible
    }

    // drain bps stores once, then backtrace
    asm volatile("s_waitcnt vmcnt(0)" ::: "memory");
    __syncthreads();

    {
      float val = vaR;
      int idx = tid;
#pragma unroll
      for (int off = 1; off < 64; off <<= 1) {
        float ov = __shfl_xor(val, off);
        int oi = __shfl_xor(idx, off);
        if (ov > val || (ov == val && oi < idx)) { val = ov; idx = oi; }
      }
      if (lane == 0) { sm.v.wvals[w] = val; sm.v.widxs[w] = idx; }
    }
    __syncthreads();
    if (tid == 0) {
      float bv = sm.v.wvals[0]; int bi = sm.v.widxs[0];
      for (int i = 1; i < 8; ++i)
        if (sm.v.wvals[i] > bv || (sm.v.wvals[i] == bv && sm.v.widxs[i] < bi)) {
          bv = sm.v.wvals[i]; bi = sm.v.widxs[i];
        }
      sm.v.lastS = bi;
    }
    __syncthreads();
    int tok = sm.v.lastS;

    // backtrace: rows 510..0, 32-row LDS chunks
    for (int cch = 15; cch >= 0; --cch) {
      int rhi = cch * 32 + 31; if (rhi > 510) rhi = 510;
      int srow = tid >> 4, part = tid & 15;
      int row = cch * 32 + srow;
      if (row <= 510) {
        const uint4* src = (const uint4*)(bps + ((size_t)row * Bn + b) * Vn);
        uint4* dst = (uint4*)&sm.v.bpbuf[srow][0];
#pragma unroll
        for (int q = 0; q < 4; ++q) dst[part * 4 + q] = src[part * 4 + q];
      }
      __syncthreads();
      if (tid == 0) {
        int tk = tok;
        for (int rr = rhi; rr >= cch * 32; --rr) {
          sm.v.tokens[rr + 1] = (unsigned short)tk;
          tk = sm.v.bpbuf[rr - cch * 32][tk];
        }
        tok = tk;
      }
      __syncthreads();
    }
    if (tid == 0) sm.v.tokens[0] = (unsigned short)tok;
    __syncthreads();
    out_tok[b * Tn + tid] = (float)sm.v.tokens[tid];
  }
}

extern "C" void kernel_launch(void* const* d_in, const int* in_sizes, int n_in,
                              void* d_out, int out_size, void* d_ws, size_t ws_size,
                              hipStream_t stream) {
  const float* x = (const float*)d_in[0];
  const float* w = (const float*)d_in[1];
  const float* trans = (const float*)d_in[2];
  const int* tgt = (const int*)d_in[3];
  const unsigned char* pad = (const unsigned char*)d_in[4];
  float* out = (float*)d_out;

  char* ws = (char*)d_ws;
  float* Rp = (float*)ws;                                    // 64 B
  h1* E4 = (h1*)(ws + 64);                                   // 512 KB
  unsigned short* bps = (unsigned short*)(ws + 64 + 524288); // ~16.7 MB

  float* emis = out;                 // (B,T,V)
  float* out_ll = out + 8388608;     // (B,)
  float* out_tok = out + 8388640;    // (B,T) as float

  hipMemsetAsync(Rp, 0, 4, stream);
  hipLaunchKernelGGL(crf_minmax, dim3(8), dim3(512), 0, stream, trans, (unsigned int*)Rp);
  hipLaunchKernelGGL(crf_build_E4, dim3(512), dim3(256), 0, stream, trans, E4);
  hipLaunchKernelGGL(crf_gemm, dim3(2048), dim3(256), 0, stream, x, w, emis);
  hipLaunchKernelGGL(crf_scan, dim3(64), dim3(512), 0, stream, emis, trans, E4, Rp,
                     tgt, pad, bps, out_ll, out_tok);
}

// Round 7
// 906.295 us; speedup vs baseline: 3.2907x; 3.2907x over previous
//
#include <hip/hip_runtime.h>

#define Bn 32
#define Tn 512
#define Dn 512
#define Vn 512

typedef _Float16 h1;
typedef _Float16 h8 __attribute__((ext_vector_type(8)));
typedef float f4 __attribute__((ext_vector_type(4)));

__device__ __forceinline__ float max8lds(const float* p) {
  float4 a = *(const float4*)p;
  float4 b = *(const float4*)(p + 4);
  return fmaxf(fmaxf(fmaxf(a.x, a.y), fmaxf(a.z, a.w)),
               fmaxf(fmaxf(b.x, b.y), fmaxf(b.z, b.w)));
}

// 64-lane max via DPP (row_shr 1/2/4/8 + bcast15/31), result broadcast via readlane
__device__ __forceinline__ float dpp64max(float x) {
  int t;
  t = __builtin_amdgcn_update_dpp(__float_as_int(x), __float_as_int(x), 0x111, 0xF, 0xF, false);
  x = fmaxf(x, __int_as_float(t));
  t = __builtin_amdgcn_update_dpp(__float_as_int(x), __float_as_int(x), 0x112, 0xF, 0xF, false);
  x = fmaxf(x, __int_as_float(t));
  t = __builtin_amdgcn_update_dpp(__float_as_int(x), __float_as_int(x), 0x114, 0xF, 0xF, false);
  x = fmaxf(x, __int_as_float(t));
  t = __builtin_amdgcn_update_dpp(__float_as_int(x), __float_as_int(x), 0x118, 0xF, 0xF, false);
  x = fmaxf(x, __int_as_float(t));
  t = __builtin_amdgcn_update_dpp(__float_as_int(x), __float_as_int(x), 0x142, 0xF, 0xF, false);
  x = fmaxf(x, __int_as_float(t));
  t = __builtin_amdgcn_update_dpp(__float_as_int(x), __float_as_int(x), 0x143, 0xF, 0xF, false);
  x = fmaxf(x, __int_as_float(t));
  return __int_as_float(__builtin_amdgcn_readlane(__float_as_int(x), 63));
}

// raw barrier: LDS-visibility only (no vmcnt drain -> global ops float across steps)
__device__ __forceinline__ void bar_lgkm() {
  asm volatile("s_waitcnt lgkmcnt(0)" ::: "memory");
  __builtin_amdgcn_s_barrier();
}

// ---- pruning radius: max over columns v of (max_u T[u][v] - min_u T[u][v]) ----
// grid 8, block 512; block handles 64 cols; atomicMax(float-bits) into Rout (pre-zeroed)
__global__ __launch_bounds__(512) void crf_minmax(const float* __restrict__ trans,
                                                  unsigned int* __restrict__ Rout) {
  __shared__ float smn[8][64], smx[8][64];
  const int c = threadIdx.x & 63;
  const int seg = threadIdx.x >> 6;
  const int col = (int)blockIdx.x * 64 + c;
  float mn = 3e38f, mx = -3e38f;
#pragma unroll 4
  for (int u = seg * 64; u < seg * 64 + 64; ++u) {
    float t = trans[(size_t)u * Vn + col];
    mn = fminf(mn, t); mx = fmaxf(mx, t);
  }
  smn[seg][c] = mn; smx[seg][c] = mx;
  __syncthreads();
  if (seg == 0) {
#pragma unroll
    for (int i = 1; i < 8; ++i) { mn = fminf(mn, smn[i][c]); mx = fmaxf(mx, smx[i][c]); }
    float r = dpp64max(mx - mn);  // r >= 0
    if (c == 0) atomicMax((int*)Rout, __float_as_int(r));
  }
}

// ---- E4: exp(trans) arranged as MFMA A-fragments ----
// frag element (vt, kc, lane, j) = exp(trans[u][v]),
//   u = kc*32 + 8*(lane>>4) + j,  v = vt*16 + (lane&15)
__global__ __launch_bounds__(256) void crf_build_E4(const float* __restrict__ trans,
                                                    h1* __restrict__ E4) {
  __shared__ float tl[32][17];
  const int vt = (int)blockIdx.x >> 4, kc = (int)blockIdx.x & 15;
  const int tid = threadIdx.x;
#pragma unroll
  for (int rep = 0; rep < 2; ++rep) {
    int l = tid + rep * 256;
    int ul = l >> 4, vl = l & 15;
    tl[ul][vl] = trans[(size_t)(kc * 32 + ul) * Vn + (vt * 16 + vl)];
  }
  __syncthreads();
  const int lane = tid & 63, jp = tid >> 6;
  const int g = lane >> 4, c = lane & 15;
#pragma unroll
  for (int j2 = 0; j2 < 2; ++j2) {
    int j = jp * 2 + j2;
    float e = __expf(tl[8 * g + j][c]);
    E4[((size_t)(vt * 16 + kc) * 64 + lane) * 8 + j] = (h1)e;
  }
}

// ---- emissions = X(16384x512) * W^T(512x512), f32, 64x64 tile BK=16 ----
__global__ __launch_bounds__(256) void crf_gemm(const float* __restrict__ X,
                                                const float* __restrict__ Wt,
                                                float* __restrict__ C) {
  __shared__ float As[16][68];
  __shared__ float Bs[16][68];
  const int tid = threadIdx.x;
  const int m0 = (int)(blockIdx.x >> 3) * 64;
  const int v0 = (int)(blockIdx.x & 7) * 64;
  const int lr = tid >> 2;
  const int lk = (tid & 3) * 4;
  const int ty = tid >> 4, tx = tid & 15;
  float acc[4][4] = {};
  const float* xrow = X + (size_t)(m0 + lr) * Dn + lk;
  const float* wrow = Wt + (size_t)(v0 + lr) * Dn + lk;
  for (int k0 = 0; k0 < Dn; k0 += 16) {
    float4 av = *(const float4*)(xrow + k0);
    float4 bv = *(const float4*)(wrow + k0);
    __syncthreads();
    As[lk + 0][lr] = av.x; As[lk + 1][lr] = av.y; As[lk + 2][lr] = av.z; As[lk + 3][lr] = av.w;
    Bs[lk + 0][lr] = bv.x; Bs[lk + 1][lr] = bv.y; Bs[lk + 2][lr] = bv.z; Bs[lk + 3][lr] = bv.w;
    __syncthreads();
#pragma unroll
    for (int kk = 0; kk < 16; ++kk) {
      float4 a = *(const float4*)&As[kk][ty * 4];
      float4 b4 = *(const float4*)&Bs[kk][tx * 4];
      float a_[4] = {a.x, a.y, a.z, a.w};
      float b_[4] = {b4.x, b4.y, b4.z, b4.w};
#pragma unroll
      for (int j = 0; j < 4; ++j)
#pragma unroll
        for (int i = 0; i < 4; ++i)
          acc[j][i] = fmaf(a_[j], b_[i], acc[j][i]);
    }
  }
#pragma unroll
  for (int j = 0; j < 4; ++j) {
    float4 o; o.x = acc[j][0]; o.y = acc[j][1]; o.z = acc[j][2]; o.w = acc[j][3];
    *(float4*)(C + (size_t)(m0 + ty * 4 + j) * Vn + v0 + tx * 4) = o;
  }
}

// ---- shared-memory union: forward vs viterbi roles ----
union SM {
  struct {
    __align__(16) uint4 ldsA[8 * 4 * 4 * 64];  // 128 KB: kc 12..15 A-frags
    __align__(16) h1 ph[2][Vn];                // parity-double-buffered p
    __align__(16) float wred[2][8];            // parity-double-buffered wave maxes
    __align__(16) float wred2[8];
    unsigned char padsh[Tn];
  } f;
  struct {
    __align__(16) float va2[2][Vn];
    __align__(16) unsigned short bpbuf[32][Vn];
    unsigned short tokens[Tn];
    __align__(16) float wvals[8];
    int widxs[8];
    unsigned char padsh[Tn];
    int lastS;
  } v;
};

// ---- fused scan: blocks 0..31 forward(logZ,loglik); 32..63 viterbi+backtrace ----
__global__ __launch_bounds__(512, 2) void crf_scan(
    const float* __restrict__ emis, const float* __restrict__ trans,
    const h1* __restrict__ E4, const float* __restrict__ Rp,
    const int* __restrict__ tgt, const unsigned char* __restrict__ pad,
    unsigned short* __restrict__ bps, float* __restrict__ out_ll,
    float* __restrict__ out_tok) {
  __shared__ SM sm;

  const int tid = threadIdx.x;
  const int b = blockIdx.x & 31;
  const int role = blockIdx.x >> 5;
  const float* eb = emis + (size_t)b * Tn * Vn;
  const int w = tid >> 6;
  const int lane = tid & 63;

  if (role == 0) {
    // ========== FORWARD (logsumexp via MFMA, 1 barrier/step, DPP max) ==========
    const int g = lane >> 4, c = lane & 15;
    const int t2sel = c >> 2, r2sel = c & 3;
    const int sidx = ((16 * ((lane >> 2) & 3)) + 4 * (lane >> 4) + (lane & 3)) << 2;
    const h8* E4v = (const h8*)E4;
    h8 EA[4][12];
#pragma unroll
    for (int vt2 = 0; vt2 < 4; ++vt2)
#pragma unroll
      for (int kc = 0; kc < 12; ++kc)
        EA[vt2][kc] = E4v[(size_t)((4 * w + vt2) * 16 + kc) * 64 + lane];
    {
      const uint4* E4u = (const uint4*)E4;
#pragma unroll
      for (int vt2 = 0; vt2 < 4; ++vt2)
#pragma unroll
        for (int k2 = 0; k2 < 4; ++k2)
          sm.f.ldsA[(((w * 4 + vt2) * 4) + k2) * 64 + lane] =
              E4u[(size_t)((4 * w + vt2) * 16 + (12 + k2)) * 64 + lane];
    }
    sm.f.padsh[tid] = pad[b * Tn + tid];
    float alphaR = eb[tid];
    float ecur = eb[Vn + tid];
    {
      float r = dpp64max(alphaR);
      if (lane == 0) sm.f.wred[0][w] = r;
    }
    bar_lgkm();
    float m_used = max8lds(sm.f.wred[0]);  // exact max(alpha_0)

    for (int t = 1; t < Tn; ++t) {
      const int q = t & 1;
      float p = __expf(fminf(alphaR - m_used, 11.0f));
      sm.f.ph[q][tid] = (h1)p;
      bar_lgkm();  // ph[q] + wred[q^1] (written end of t-1) visible
      float m_next = max8lds(sm.f.wred[q ^ 1]);  // exact max(alpha_{t-1})
      float enext = (t + 1 < Tn) ? eb[(size_t)(t + 1) * Vn + tid] : 0.f;
      f4 acc0 = (f4)(0.f), acc1 = (f4)(0.f), acc2 = (f4)(0.f), acc3 = (f4)(0.f);
      const h8* phf = (const h8*)sm.f.ph[q];
#pragma unroll
      for (int kc = 0; kc < 12; ++kc) {
        h8 pb = phf[kc * 4 + g];
        acc0 = __builtin_amdgcn_mfma_f32_16x16x32_f16(EA[0][kc], pb, acc0, 0, 0, 0);
        acc1 = __builtin_amdgcn_mfma_f32_16x16x32_f16(EA[1][kc], pb, acc1, 0, 0, 0);
        acc2 = __builtin_amdgcn_mfma_f32_16x16x32_f16(EA[2][kc], pb, acc2, 0, 0, 0);
        acc3 = __builtin_amdgcn_mfma_f32_16x16x32_f16(EA[3][kc], pb, acc3, 0, 0, 0);
      }
#pragma unroll
      for (int k2 = 0; k2 < 4; ++k2) {
        h8 pb = phf[(12 + k2) * 4 + g];
        h8 a0 = *(const h8*)&sm.f.ldsA[(((w * 4 + 0) * 4) + k2) * 64 + lane];
        h8 a1 = *(const h8*)&sm.f.ldsA[(((w * 4 + 1) * 4) + k2) * 64 + lane];
        h8 a2 = *(const h8*)&sm.f.ldsA[(((w * 4 + 2) * 4) + k2) * 64 + lane];
        h8 a3 = *(const h8*)&sm.f.ldsA[(((w * 4 + 3) * 4) + k2) * 64 + lane];
        acc0 = __builtin_amdgcn_mfma_f32_16x16x32_f16(a0, pb, acc0, 0, 0, 0);
        acc1 = __builtin_amdgcn_mfma_f32_16x16x32_f16(a1, pb, acc1, 0, 0, 0);
        acc2 = __builtin_amdgcn_mfma_f32_16x16x32_f16(a2, pb, acc2, 0, 0, 0);
        acc3 = __builtin_amdgcn_mfma_f32_16x16x32_f16(a3, pb, acc3, 0, 0, 0);
      }
      // present value for v-slot 16*(c>>2)+4g+(c&3); pull via one intra-wave bpermute
      f4 at = (t2sel == 0) ? acc0 : (t2sel == 1) ? acc1 : (t2sel == 2) ? acc2 : acc3;
      float lo = (r2sel & 1) ? at[1] : at[0];
      float hi = (r2sel & 1) ? at[3] : at[2];
      float tot = (r2sel & 2) ? hi : lo;
      float tv = __int_as_float(__builtin_amdgcn_ds_bpermute(sidx, __float_as_int(tot)));
      float nv = m_used + __logf(tv) + ecur;
      if (sm.f.padsh[t]) nv = alphaR;
      alphaR = nv; ecur = enext;
      float rmx = dpp64max(nv);
      if (lane == 0) sm.f.wred[q][w] = rmx;  // visible after next iter's barrier
      m_used = m_next;
    }

    // epilogue: logZ + gold score
    __syncthreads();
    float m = max8lds(sm.f.wred[1]);  // max(alpha_511)
    float ex = __expf(alphaR - m);
#pragma unroll
    for (int off = 1; off < 64; off <<= 1) ex += __shfl_xor(ex, off);
    if (lane == 0) sm.f.wred[0][w] = ex;
    float sc;
    {
      int t = tid;
      int tg = tgt[b * Tn + t];
      float mt = sm.f.padsh[t] ? 0.f : 1.f;
      sc = eb[(size_t)t * Vn + tg] * mt;
      if (t < Tn - 1) {
        int tg1 = tgt[b * Tn + t + 1];
        float mt1 = sm.f.padsh[t + 1] ? 0.f : 1.f;
        sc += trans[(size_t)tg * Vn + tg1] * mt * mt1;
      }
    }
#pragma unroll
    for (int off = 1; off < 64; off <<= 1) sc += __shfl_xor(sc, off);
    if (lane == 0) sm.f.wred2[w] = sc;
    __syncthreads();
    if (tid == 0) {
      float s = 0.f, gg = 0.f;
      for (int i = 0; i < 8; ++i) { s += sm.f.wred[0][i]; gg += sm.f.wred2[i]; }
      out_ll[b] = gg - (m + __logf(s));
    }
  } else {
    // ========== VITERBI (1 barrier/step, GLOBAL threshold, wave-redundant masks) ==========
    float R = __int_as_float(((const int*)Rp)[0]) * 1.000001f + 1e-4f;
    sm.v.padsh[tid] = pad[b * Tn + tid];
    float vaR = eb[tid];
    sm.v.va2[0][tid] = vaR;
    float ecur = eb[Vn + tid];
    bar_lgkm();

    for (int t = 1; t < Tn; ++t) {
      const int cur = t & 1, prev = cur ^ 1;
      const float* va2p = sm.v.va2[prev];
      // every wave redundantly: read full va (8/lane), global max, candidate masks
      const float4* vap4 = (const float4*)va2p;
      float4 q0 = vap4[lane * 2];
      float4 q1 = vap4[lane * 2 + 1];
      float mx8 = fmaxf(fmaxf(fmaxf(q0.x, q0.y), fmaxf(q0.z, q0.w)),
                        fmaxf(fmaxf(q1.x, q1.y), fmaxf(q1.z, q1.w)));
      float gmax = dpp64max(mx8);
      float thr = gmax - R;
      unsigned long long bm[8];
      bm[0] = __ballot(q0.x >= thr);
      bm[1] = __ballot(q0.y >= thr);
      bm[2] = __ballot(q0.z >= thr);
      bm[3] = __ballot(q0.w >= thr);
      bm[4] = __ballot(q1.x >= thr);
      bm[5] = __ballot(q1.y >= thr);
      bm[6] = __ballot(q1.z >= thr);
      bm[7] = __ballot(q1.w >= thr);
      unsigned long long any = bm[0] | bm[1] | bm[2] | bm[3] |
                               bm[4] | bm[5] | bm[6] | bm[7];
      float enext = (t + 1 < Tn) ? eb[(size_t)(t + 1) * Vn + tid] : 0.f;
      float best = -3e38f; int arg = 0;
      while (any) {  // ascending l (wave-uniform), j ascending -> ascending u
        int l = __ffsll(any) - 1; any &= any - 1;
#pragma unroll
        for (int j = 0; j < 8; ++j) {
          if ((bm[j] >> l) & 1) {
            int u = 8 * l + j;
            float cnd = va2p[u] + trans[(size_t)u * Vn + tid];
            if (cnd > best) { best = cnd; arg = u; }
          }
        }
      }
      float nv = best + ecur; int bp = arg;
      if (sm.v.padsh[t]) { nv = vaR; bp = tid; }
      bps[((size_t)(t - 1) * Bn + b) * Vn + tid] = (unsigned short)bp;  // floats free
      sm.v.va2[cur][tid] = nv;
      vaR = nv; ecur = enext;
      bar_lgkm();  // single barrier: va2[cur] visible
    }

    // drain bps stores once, then backtrace
    asm volatile("s_waitcnt vmcnt(0)" ::: "memory");
    __syncthreads();

    {
      float val = vaR;
      int idx = tid;
#pragma unroll
      for (int off = 1; off < 64; off <<= 1) {
        float ov = __shfl_xor(val, off);
        int oi = __shfl_xor(idx, off);
        if (ov > val || (ov == val && oi < idx)) { val = ov; idx = oi; }
      }
      if (lane == 0) { sm.v.wvals[w] = val; sm.v.widxs[w] = idx; }
    }
    __syncthreads();
    if (tid == 0) {
      float bv = sm.v.wvals[0]; int bi = sm.v.widxs[0];
      for (int i = 1; i < 8; ++i)
        if (sm.v.wvals[i] > bv || (sm.v.wvals[i] == bv && sm.v.widxs[i] < bi)) {
          bv = sm.v.wvals[i]; bi = sm.v.widxs[i];
        }
      sm.v.lastS = bi;
    }
    __syncthreads();
    int tok = sm.v.lastS;

    // backtrace: rows 510..0, 32-row LDS chunks
    for (int cch = 15; cch >= 0; --cch) {
      int rhi = cch * 32 + 31; if (rhi > 510) rhi = 510;
      int srow = tid >> 4, part = tid & 15;
      int row = cch * 32 + srow;
      if (row <= 510) {
        const uint4* src = (const uint4*)(bps + ((size_t)row * Bn + b) * Vn);
        uint4* dst = (uint4*)&sm.v.bpbuf[srow][0];
#pragma unroll
        for (int qq = 0; qq < 4; ++qq) dst[part * 4 + qq] = src[part * 4 + qq];
      }
      __syncthreads();
      if (tid == 0) {
        int tk = tok;
        for (int rr = rhi; rr >= cch * 32; --rr) {
          sm.v.tokens[rr + 1] = (unsigned short)tk;
          tk = sm.v.bpbuf[rr - cch * 32][tk];
        }
        tok = tk;
      }
      __syncthreads();
    }
    if (tid == 0) sm.v.tokens[0] = (unsigned short)tok;
    __syncthreads();
    out_tok[b * Tn + tid] = (float)sm.v.tokens[tid];
  }
}

extern "C" void kernel_launch(void* const* d_in, const int* in_sizes, int n_in,
                              void* d_out, int out_size, void* d_ws, size_t ws_size,
                              hipStream_t stream) {
  const float* x = (const float*)d_in[0];
  const float* w = (const float*)d_in[1];
  const float* trans = (const float*)d_in[2];
  const int* tgt = (const int*)d_in[3];
  const unsigned char* pad = (const unsigned char*)d_in[4];
  float* out = (float*)d_out;

  char* ws = (char*)d_ws;
  float* Rp = (float*)ws;                                    // 64 B
  h1* E4 = (h1*)(ws + 64);                                   // 512 KB
  unsigned short* bps = (unsigned short*)(ws + 64 + 524288); // ~16.7 MB

  float* emis = out;                 // (B,T,V)
  float* out_ll = out + 8388608;     // (B,)
  float* out_tok = out + 8388640;    // (B,T) as float

  hipMemsetAsync(Rp, 0, 4, stream);
  hipLaunchKernelGGL(crf_minmax, dim3(8), dim3(512), 0, stream, trans, (unsigned int*)Rp);
  hipLaunchKernelGGL(crf_build_E4, dim3(512), dim3(256), 0, stream, trans, E4);
  hipLaunchKernelGGL(crf_gemm, dim3(2048), dim3(256), 0, stream, x, w, emis);
  hipLaunchKernelGGL(crf_scan, dim3(64), dim3(512), 0, stream, emis, trans, E4, Rp,
                     tgt, pad, bps, out_ll, out_tok);
}

// Round 8
// 720.843 us; speedup vs baseline: 4.1373x; 1.2573x over previous
//
#include <hip/hip_runtime.h>

#define Bn 32
#define Tn 512
#define Dn 512
#define Vn 512

typedef _Float16 h1;
typedef float f4 __attribute__((ext_vector_type(4)));
typedef int i8v __attribute__((ext_vector_type(8)));

__device__ __forceinline__ float max8lds(const float* p) {
  float4 a = *(const float4*)p;
  float4 b = *(const float4*)(p + 4);
  return fmaxf(fmaxf(fmaxf(a.x, a.y), fmaxf(a.z, a.w)),
               fmaxf(fmaxf(b.x, b.y), fmaxf(b.z, b.w)));
}

// 64-lane max via DPP (row_shr 1/2/4/8 + bcast15/31), result broadcast via readlane
__device__ __forceinline__ float dpp64max(float x) {
  int t;
  t = __builtin_amdgcn_update_dpp(__float_as_int(x), __float_as_int(x), 0x111, 0xF, 0xF, false);
  x = fmaxf(x, __int_as_float(t));
  t = __builtin_amdgcn_update_dpp(__float_as_int(x), __float_as_int(x), 0x112, 0xF, 0xF, false);
  x = fmaxf(x, __int_as_float(t));
  t = __builtin_amdgcn_update_dpp(__float_as_int(x), __float_as_int(x), 0x114, 0xF, 0xF, false);
  x = fmaxf(x, __int_as_float(t));
  t = __builtin_amdgcn_update_dpp(__float_as_int(x), __float_as_int(x), 0x118, 0xF, 0xF, false);
  x = fmaxf(x, __int_as_float(t));
  t = __builtin_amdgcn_update_dpp(__float_as_int(x), __float_as_int(x), 0x142, 0xF, 0xF, false);
  x = fmaxf(x, __int_as_float(t));
  t = __builtin_amdgcn_update_dpp(__float_as_int(x), __float_as_int(x), 0x143, 0xF, 0xF, false);
  x = fmaxf(x, __int_as_float(t));
  return __int_as_float(__builtin_amdgcn_readlane(__float_as_int(x), 63));
}

// raw barrier: LDS-visibility only (no vmcnt drain -> global ops float across steps)
__device__ __forceinline__ void bar_lgkm() {
  asm volatile("s_waitcnt lgkmcnt(0)" ::: "memory");
  __builtin_amdgcn_s_barrier();
}

// ---- f32 -> OCP e4m3fn, round-to-nearest-even (x >= 0 assumed) ----
__device__ __forceinline__ unsigned int f32_to_e4m3(float x) {
  x = fminf(x, 448.0f);
  unsigned int bits = __float_as_uint(x);
  int e = (int)((bits >> 23) & 0xFF) - 127;
  if (e < -6) {
    // subnormal target: round(x * 2^9) in 0..8 (8 == 2^-6 normal, byte 0x08)
    return (unsigned int)__float2int_rn(x * 512.0f);
  }
  unsigned int man = bits & 0x7FFFFF;
  int te = e + 7;
  unsigned int r = man >> 20;
  unsigned int rem = man & 0xFFFFF;
  if (rem > 0x80000u || (rem == 0x80000u && (r & 1u))) r++;
  if (r == 8u) { r = 0u; te++; }
  if (te > 15) { te = 15; r = 6u; }
  unsigned int byte = ((unsigned int)te << 3) | r;
  if (byte > 0x7Eu) byte = 0x7Eu;
  return byte;
}

// ---- pruning radius: max over columns v of (max_u T[u][v] - min_u T[u][v]) ----
__global__ __launch_bounds__(512) void crf_minmax(const float* __restrict__ trans,
                                                  unsigned int* __restrict__ Rout) {
  __shared__ float smn[8][64], smx[8][64];
  const int c = threadIdx.x & 63;
  const int seg = threadIdx.x >> 6;
  const int col = (int)blockIdx.x * 64 + c;
  float mn = 3e38f, mx = -3e38f;
#pragma unroll 4
  for (int u = seg * 64; u < seg * 64 + 64; ++u) {
    float t = trans[(size_t)u * Vn + col];
    mn = fminf(mn, t); mx = fmaxf(mx, t);
  }
  smn[seg][c] = mn; smx[seg][c] = mx;
  __syncthreads();
  if (seg == 0) {
#pragma unroll
    for (int i = 1; i < 8; ++i) { mn = fminf(mn, smn[i][c]); mx = fmaxf(mx, smx[i][c]); }
    float r = dpp64max(mx - mn);  // r >= 0
    if (c == 0) atomicMax((int*)Rout, __float_as_int(r));
  }
}

// ---- E8: exp(trans) as fp8 e4m3 MFMA A-fragments for 16x16x128 ----
// frag (vt, kc): byte index = lane*32 + j
//   u = kc*128 + 32*(lane>>4) + j,  v = vt*16 + (lane&15)
// stored at E8[(vt*4 + kc)*2048 + lane*32 + j]
__global__ __launch_bounds__(256) void crf_build_E8(const float* __restrict__ trans,
                                                    unsigned char* __restrict__ E8) {
  const int fid = (int)blockIdx.x;       // 0..127 = vt*4 + kc
  const int vt = fid >> 2, kc = fid & 3;
  const int t = threadIdx.x;             // 8 bytes per thread
  const int lane = t >> 2;
  const int j0 = (t & 3) * 8;
  const int v = vt * 16 + (lane & 15);
  const int ubase = kc * 128 + (lane >> 4) * 32 + j0;
  unsigned long long pack = 0;
#pragma unroll
  for (int s = 0; s < 8; ++s) {
    float e = __expf(trans[(size_t)(ubase + s) * Vn + v]);
    pack |= (unsigned long long)f32_to_e4m3(e) << (8 * s);
  }
  *(unsigned long long*)(E8 + (size_t)fid * 2048 + lane * 32 + j0) = pack;
}

// ---- emissions = X(16384x512) * W^T(512x512), f32, 64x64 tile BK=16 ----
__global__ __launch_bounds__(256) void crf_gemm(const float* __restrict__ X,
                                                const float* __restrict__ Wt,
                                                float* __restrict__ C) {
  __shared__ float As[16][68];
  __shared__ float Bs[16][68];
  const int tid = threadIdx.x;
  const int m0 = (int)(blockIdx.x >> 3) * 64;
  const int v0 = (int)(blockIdx.x & 7) * 64;
  const int lr = tid >> 2;
  const int lk = (tid & 3) * 4;
  const int ty = tid >> 4, tx = tid & 15;
  float acc[4][4] = {};
  const float* xrow = X + (size_t)(m0 + lr) * Dn + lk;
  const float* wrow = Wt + (size_t)(v0 + lr) * Dn + lk;
  for (int k0 = 0; k0 < Dn; k0 += 16) {
    float4 av = *(const float4*)(xrow + k0);
    float4 bv = *(const float4*)(wrow + k0);
    __syncthreads();
    As[lk + 0][lr] = av.x; As[lk + 1][lr] = av.y; As[lk + 2][lr] = av.z; As[lk + 3][lr] = av.w;
    Bs[lk + 0][lr] = bv.x; Bs[lk + 1][lr] = bv.y; Bs[lk + 2][lr] = bv.z; Bs[lk + 3][lr] = bv.w;
    __syncthreads();
#pragma unroll
    for (int kk = 0; kk < 16; ++kk) {
      float4 a = *(const float4*)&As[kk][ty * 4];
      float4 b4 = *(const float4*)&Bs[kk][tx * 4];
      float a_[4] = {a.x, a.y, a.z, a.w};
      float b_[4] = {b4.x, b4.y, b4.z, b4.w};
#pragma unroll
      for (int j = 0; j < 4; ++j)
#pragma unroll
        for (int i = 0; i < 4; ++i)
          acc[j][i] = fmaf(a_[j], b_[i], acc[j][i]);
    }
  }
#pragma unroll
  for (int j = 0; j < 4; ++j) {
    float4 o; o.x = acc[j][0]; o.y = acc[j][1]; o.z = acc[j][2]; o.w = acc[j][3];
    *(float4*)(C + (size_t)(m0 + ty * 4 + j) * Vn + v0 + tx * 4) = o;
  }
}

// ---- shared-memory union: forward vs viterbi roles ----
union SM {
  struct {
    __align__(16) unsigned char ph[Vn];   // fp8 p broadcast (512 B)
    __align__(16) float wred[8];
    __align__(16) float wred2[8];
    unsigned char padsh[Tn];
  } f;
  struct {
    __align__(16) float va2[2][Vn];
    __align__(16) unsigned short bpbuf[32][Vn];
    unsigned short tokens[Tn];
    __align__(16) float wvals[8];
    int widxs[8];
    unsigned char padsh[Tn];
    int lastS;
  } v;
};

// ---- fused scan: blocks 0..31 forward(logZ,loglik); 32..63 viterbi+backtrace ----
__global__ __launch_bounds__(512, 2) void crf_scan(
    const float* __restrict__ emis, const float* __restrict__ trans,
    const unsigned char* __restrict__ E8, const float* __restrict__ Rp,
    const int* __restrict__ tgt, const unsigned char* __restrict__ pad,
    unsigned short* __restrict__ bps, float* __restrict__ out_ll,
    float* __restrict__ out_tok) {
  __shared__ SM sm;

  const int tid = threadIdx.x;
  const int b = blockIdx.x & 31;
  const int role = blockIdx.x >> 5;
  const float* eb = emis + (size_t)b * Tn * Vn;
  const int w = tid >> 6;
  const int lane = tid & 63;

  if (role == 0) {
    // ========== FORWARD (logsumexp via MX-FP8 MFMA K=128, exact-m 2-barrier) ==========
    const int g = lane >> 4, c = lane & 15;
    const int t2sel = c >> 2, r2sel = c & 3;
    const int sidx = ((16 * ((lane >> 2) & 3)) + 4 * (lane >> 4) + (lane & 3)) << 2;
    // all of E resident: 4 v-tiles x 4 kc x 8 dwords = 128 VGPRs
    i8v EA[4][4];
    {
      const i8v* E8v = (const i8v*)E8;
#pragma unroll
      for (int vt2 = 0; vt2 < 4; ++vt2)
#pragma unroll
        for (int kc = 0; kc < 4; ++kc)
          EA[vt2][kc] = E8v[((4 * w + vt2) * 4 + kc) * 64 + lane];
    }
    sm.f.padsh[tid] = pad[b * Tn + tid];
    float alphaR = eb[tid];
    float ecur = eb[Vn + tid];
    {
      float r = dpp64max(alphaR);
      if (lane == 0) sm.f.wred[w] = r;
    }
    bar_lgkm();
    float m = max8lds(sm.f.wred);  // exact max(alpha_{t-1}) at loop top

    for (int t = 1; t < Tn; ++t) {
      float p = __expf(alphaR - m);            // p in (0, 1]
      sm.f.ph[tid] = (unsigned char)f32_to_e4m3(p);
      bar_lgkm();  // A: ph visible
      float enext = (t + 1 < Tn) ? eb[(size_t)(t + 1) * Vn + tid] : 0.f;
      // B fragments: 32 bytes per lane-group g per kc (broadcast reads)
      const uint4* phq = (const uint4*)sm.f.ph;
      i8v B4[4];
#pragma unroll
      for (int kc = 0; kc < 4; ++kc) {
        union { uint4 u[2]; i8v v; } bu;
        bu.u[0] = phq[kc * 8 + g * 2];
        bu.u[1] = phq[kc * 8 + g * 2 + 1];
        B4[kc] = bu.v;
      }
      f4 acc0 = (f4)(0.f), acc1 = (f4)(0.f), acc2 = (f4)(0.f), acc3 = (f4)(0.f);
#pragma unroll
      for (int kc = 0; kc < 4; ++kc) {
        acc0 = __builtin_amdgcn_mfma_scale_f32_16x16x128_f8f6f4(
            EA[0][kc], B4[kc], acc0, 0, 0, 0, 0x7F7F7F7F, 0, 0x7F7F7F7F);
        acc1 = __builtin_amdgcn_mfma_scale_f32_16x16x128_f8f6f4(
            EA[1][kc], B4[kc], acc1, 0, 0, 0, 0x7F7F7F7F, 0, 0x7F7F7F7F);
        acc2 = __builtin_amdgcn_mfma_scale_f32_16x16x128_f8f6f4(
            EA[2][kc], B4[kc], acc2, 0, 0, 0, 0x7F7F7F7F, 0, 0x7F7F7F7F);
        acc3 = __builtin_amdgcn_mfma_scale_f32_16x16x128_f8f6f4(
            EA[3][kc], B4[kc], acc3, 0, 0, 0, 0x7F7F7F7F, 0, 0x7F7F7F7F);
      }
      // lane (g,c) holds D[4g+r][c] of tile t2sel; one intra-wave bpermute redistributes
      f4 at = (t2sel == 0) ? acc0 : (t2sel == 1) ? acc1 : (t2sel == 2) ? acc2 : acc3;
      float lo = (r2sel & 1) ? at[1] : at[0];
      float hi = (r2sel & 1) ? at[3] : at[2];
      float tot = (r2sel & 2) ? hi : lo;
      float tv = __int_as_float(__builtin_amdgcn_ds_bpermute(sidx, __float_as_int(tot)));
      float nv = m + __logf(tv) + ecur;
      if (sm.f.padsh[t]) nv = alphaR;
      alphaR = nv; ecur = enext;
      float rmx = dpp64max(nv);
      if (lane == 0) sm.f.wred[w] = rmx;
      bar_lgkm();  // B: wred visible; ph safe to overwrite next iter
      m = max8lds(sm.f.wred);  // exact max(alpha_t)
    }

    // epilogue: logZ + gold score (m = exact max alpha_511)
    __syncthreads();
    float ex = __expf(alphaR - m);
#pragma unroll
    for (int off = 1; off < 64; off <<= 1) ex += __shfl_xor(ex, off);
    if (lane == 0) sm.f.wred[w] = ex;
    float sc;
    {
      int t = tid;
      int tg = tgt[b * Tn + t];
      float mt = sm.f.padsh[t] ? 0.f : 1.f;
      sc = eb[(size_t)t * Vn + tg] * mt;
      if (t < Tn - 1) {
        int tg1 = tgt[b * Tn + t + 1];
        float mt1 = sm.f.padsh[t + 1] ? 0.f : 1.f;
        sc += trans[(size_t)tg * Vn + tg1] * mt * mt1;
      }
    }
#pragma unroll
    for (int off = 1; off < 64; off <<= 1) sc += __shfl_xor(sc, off);
    if (lane == 0) sm.f.wred2[w] = sc;
    __syncthreads();
    if (tid == 0) {
      float s = 0.f, gg = 0.f;
      for (int i = 0; i < 8; ++i) { s += sm.f.wred[i]; gg += sm.f.wred2[i]; }
      out_ll[b] = gg - (m + __logf(s));
    }
  } else {
    // ========== VITERBI (1 barrier/step, GLOBAL threshold, wave-redundant masks) ==========
    float R = __int_as_float(((const int*)Rp)[0]) * 1.000001f + 1e-4f;
    sm.v.padsh[tid] = pad[b * Tn + tid];
    float vaR = eb[tid];
    sm.v.va2[0][tid] = vaR;
    float ecur = eb[Vn + tid];
    bar_lgkm();

    for (int t = 1; t < Tn; ++t) {
      const int cur = t & 1, prev = cur ^ 1;
      const float* va2p = sm.v.va2[prev];
      const float4* vap4 = (const float4*)va2p;
      float4 q0 = vap4[lane * 2];
      float4 q1 = vap4[lane * 2 + 1];
      float mx8 = fmaxf(fmaxf(fmaxf(q0.x, q0.y), fmaxf(q0.z, q0.w)),
                        fmaxf(fmaxf(q1.x, q1.y), fmaxf(q1.z, q1.w)));
      float gmax = dpp64max(mx8);
      float thr = gmax - R;
      unsigned long long bm[8];
      bm[0] = __ballot(q0.x >= thr);
      bm[1] = __ballot(q0.y >= thr);
      bm[2] = __ballot(q0.z >= thr);
      bm[3] = __ballot(q0.w >= thr);
      bm[4] = __ballot(q1.x >= thr);
      bm[5] = __ballot(q1.y >= thr);
      bm[6] = __ballot(q1.z >= thr);
      bm[7] = __ballot(q1.w >= thr);
      unsigned long long any = bm[0] | bm[1] | bm[2] | bm[3] |
                               bm[4] | bm[5] | bm[6] | bm[7];
      float enext = (t + 1 < Tn) ? eb[(size_t)(t + 1) * Vn + tid] : 0.f;
      float best = -3e38f; int arg = 0;
      while (any) {  // ascending l (wave-uniform), j ascending -> ascending u
        int l = __ffsll(any) - 1; any &= any - 1;
#pragma unroll
        for (int j = 0; j < 8; ++j) {
          if ((bm[j] >> l) & 1) {
            int u = 8 * l + j;
            float cnd = va2p[u] + trans[(size_t)u * Vn + tid];
            if (cnd > best) { best = cnd; arg = u; }
          }
        }
      }
      float nv = best + ecur; int bp = arg;
      if (sm.v.padsh[t]) { nv = vaR; bp = tid; }
      bps[((size_t)(t - 1) * Bn + b) * Vn + tid] = (unsigned short)bp;  // floats free
      sm.v.va2[cur][tid] = nv;
      vaR = nv; ecur = enext;
      bar_lgkm();  // single barrier: va2[cur] visible
    }

    // drain bps stores once, then backtrace
    asm volatile("s_waitcnt vmcnt(0)" ::: "memory");
    __syncthreads();

    {
      float val = vaR;
      int idx = tid;
#pragma unroll
      for (int off = 1; off < 64; off <<= 1) {
        float ov = __shfl_xor(val, off);
        int oi = __shfl_xor(idx, off);
        if (ov > val || (ov == val && oi < idx)) { val = ov; idx = oi; }
      }
      if (lane == 0) { sm.v.wvals[w] = val; sm.v.widxs[w] = idx; }
    }
    __syncthreads();
    if (tid == 0) {
      float bv = sm.v.wvals[0]; int bi = sm.v.widxs[0];
      for (int i = 1; i < 8; ++i)
        if (sm.v.wvals[i] > bv || (sm.v.wvals[i] == bv && sm.v.widxs[i] < bi)) {
          bv = sm.v.wvals[i]; bi = sm.v.widxs[i];
        }
      sm.v.lastS = bi;
    }
    __syncthreads();
    int tok = sm.v.lastS;

    // backtrace: rows 510..0, 32-row LDS chunks
    for (int cch = 15; cch >= 0; --cch) {
      int rhi = cch * 32 + 31; if (rhi > 510) rhi = 510;
      int srow = tid >> 4, part = tid & 15;
      int row = cch * 32 + srow;
      if (row <= 510) {
        const uint4* src = (const uint4*)(bps + ((size_t)row * Bn + b) * Vn);
        uint4* dst = (uint4*)&sm.v.bpbuf[srow][0];
#pragma unroll
        for (int qq = 0; qq < 4; ++qq) dst[part * 4 + qq] = src[part * 4 + qq];
      }
      __syncthreads();
      if (tid == 0) {
        int tk = tok;
        for (int rr = rhi; rr >= cch * 32; --rr) {
          sm.v.tokens[rr + 1] = (unsigned short)tk;
          tk = sm.v.bpbuf[rr - cch * 32][tk];
        }
        tok = tk;
      }
      __syncthreads();
    }
    if (tid == 0) sm.v.tokens[0] = (unsigned short)tok;
    __syncthreads();
    out_tok[b * Tn + tid] = (float)sm.v.tokens[tid];
  }
}

extern "C" void kernel_launch(void* const* d_in, const int* in_sizes, int n_in,
                              void* d_out, int out_size, void* d_ws, size_t ws_size,
                              hipStream_t stream) {
  const float* x = (const float*)d_in[0];
  const float* w = (const float*)d_in[1];
  const float* trans = (const float*)d_in[2];
  const int* tgt = (const int*)d_in[3];
  const unsigned char* pad = (const unsigned char*)d_in[4];
  float* out = (float*)d_out;

  char* ws = (char*)d_ws;
  float* Rp = (float*)ws;                                    // 64 B
  unsigned char* E8 = (unsigned char*)(ws + 64);             // 256 KB fp8 fragments
  unsigned short* bps = (unsigned short*)(ws + 64 + 524288); // ~16.7 MB

  float* emis = out;                 // (B,T,V)
  float* out_ll = out + 8388608;     // (B,)
  float* out_tok = out + 8388640;    // (B,T) as float

  hipMemsetAsync(Rp, 0, 4, stream);
  hipLaunchKernelGGL(crf_minmax, dim3(8), dim3(512), 0, stream, trans, (unsigned int*)Rp);
  hipLaunchKernelGGL(crf_build_E8, dim3(128), dim3(256), 0, stream, trans, E8);
  hipLaunchKernelGGL(crf_gemm, dim3(2048), dim3(256), 0, stream, x, w, emis);
  hipLaunchKernelGGL(crf_scan, dim3(64), dim3(512), 0, stream, emis, trans, E8, Rp,
                     tgt, pad, bps, out_ll, out_tok);
}